// Round 4
// baseline (860.414 us; speedup 1.0000x reference)
//
#include <hip/hip_runtime.h>
#include <hip/hip_bf16.h>

// ---------------------------------------------------------------------------
// TitansMemory: B=2, L=1024, D=M=2048, P=8, Kconv=4.
// bf16 NT-GEMM. Big GEMMs use 256xBN 8-phase pipelined kernel, BN chosen so
// grid == 256 blocks (full machine): G1 BN=192 (32x8), G3/G5 BN=128 (16x8x2),
// G2 BN=256 (8x8x3). Small GEMMs 128x64. XCD-aware block swizzle everywhere.
// Epilogue fusion: G2 silu-bf16 (z2==vf), G3 err-bf16, G7 qc, G8 gate.
// ---------------------------------------------------------------------------

#define NROWS 2048      // B*L
#define MD    2048      // D == M
#define PL    1032      // P + L
#define PLP   1152      // padded
#define NM    4194304   // 2048*2048

using bf16x8 = __attribute__((ext_vector_type(8))) __bf16;
using f32x4  = __attribute__((ext_vector_type(4))) float;
using u16x8  = __attribute__((ext_vector_type(8))) unsigned short;

__device__ __forceinline__ unsigned short f2bf(float f) {
    union { float f; unsigned int u; } c; c.f = f;
    unsigned int u = c.u;
    return (unsigned short)((u + 0x7fffu + ((u >> 16) & 1u)) >> 16);
}
__device__ __forceinline__ float bf2f(unsigned short h) {
    union { float f; unsigned int u; } c; c.u = ((unsigned int)h) << 16;
    return c.f;
}
__device__ __forceinline__ float ldf(const float* p) { return *p; }
__device__ __forceinline__ float ldf(const unsigned short* p) { return bf2f(*p); }
__device__ __forceinline__ float sigm(float x) { return 1.f / (1.f + __expf(-x)); }
__device__ __forceinline__ float silu(float x) { return x / (1.f + __expf(-x)); }

__device__ __forceinline__ float block_reduce_sum(float v) {
    __shared__ float ws[4];
    #pragma unroll
    for (int o = 32; o > 0; o >>= 1) v += __shfl_down(v, o);
    __syncthreads();
    if ((threadIdx.x & 63) == 0) ws[threadIdx.x >> 6] = v;
    __syncthreads();
    return (ws[0] + ws[1]) + (ws[2] + ws[3]);
}
__device__ __forceinline__ float block_reduce_max(float v) {
    __shared__ float wm[4];
    #pragma unroll
    for (int o = 32; o > 0; o >>= 1) v = fmaxf(v, __shfl_down(v, o));
    __syncthreads();
    if ((threadIdx.x & 63) == 0) wm[threadIdx.x >> 6] = v;
    __syncthreads();
    return fmaxf(fmaxf(wm[0], wm[1]), fmaxf(wm[2], wm[3]));
}

__device__ __forceinline__ void load_lds16(const unsigned short* g, unsigned short* l) {
    __builtin_amdgcn_global_load_lds(
        (const __attribute__((address_space(1))) unsigned int*)g,
        (__attribute__((address_space(3))) unsigned int*)l, 16, 0, 0);
}
__device__ __forceinline__ void raw_barrier() {
    __asm__ volatile("" ::: "memory");
    __builtin_amdgcn_s_barrier();
    __asm__ volatile("" ::: "memory");
}
// T1: XCD-aware bijective block remap (8 XCDs). Only if nwg % 8 == 0.
__device__ __forceinline__ void swz_bid(int& bx, int& by, int& bz) {
    const int gx = gridDim.x, gy = gridDim.y, gz = gridDim.z;
    const int nwg = gx * gy * gz;
    int id = blockIdx.x + gx * (blockIdx.y + gy * blockIdx.z);
    if ((nwg & 7) == 0) { int c = nwg >> 3; id = (id & 7) * c + (id >> 3); }
    bx = id % gx; id /= gx; by = id % gy; bz = id / gy;
}
// epi codes: 0 f32-store, 1 f32-accum, 2 bf16, 3 silu->bf16,
// 4 gate: bf16(sigm(v+gb[gc]) * (r1[off]+r2[off]))          (G8)
// 5 ctx : r=Cf[off]+v; Cf[off]=r; qh[off]=bf16(r+r2[off])   (G7 + addcvt)
// 7 err : Ch[off] = bf16(bf2f(rh[off]) - v)                 (G3 z0)
__device__ __forceinline__ void epi_store(int epi, float* Cf, unsigned short* Ch,
                                          long off, int gc, float v,
                                          const float* gbp, const float* r1z,
                                          const float* r2z, unsigned short* qhz) {
    if (epi == 0)      Cf[off] = v;
    else if (epi == 1) Cf[off] += v;
    else if (epi == 2) Ch[off] = f2bf(v);
    else if (epi == 3) Ch[off] = f2bf(silu(v));
    else if (epi == 4) Ch[off] = f2bf(sigm(v + gbp[gc]) * (r1z[off] + r2z[off]));
    else { float r = Cf[off] + v; Cf[off] = r; qhz[off] = f2bf(r + r2z[off]); }
}

// ---------------- NT GEMM 128x64 tile (small/single GEMMs) ----------------
// C[n,m] = sum_k A[n,k]*B[m,k]. BK=64, dbuf, vmcnt(6) prefetch.
__global__ __launch_bounds__(256) void gemm_nt(
    const unsigned short* __restrict__ A, const unsigned short* __restrict__ Bm,
    void* __restrict__ Cv, int Mc, int K, long sA, long sB, long sCb, int epiPack,
    const float* __restrict__ gbp, const float* __restrict__ r1,
    const float* __restrict__ r2, unsigned short* __restrict__ qh)
{
    __shared__ unsigned short As[2][8192];
    __shared__ unsigned short Bs[2][4096];
    int bxx, byy, bzz; swz_bid(bxx, byy, bzz);
    const int tid = threadIdx.x, lane = tid & 63, w = tid >> 6;
    const int l16 = lane & 15, quad = lane >> 4;
    const int wr = (w >> 1) * 64, wc = (w & 1) * 32;
    const long rowBase = (long)byy * 128;
    const long colBase = (long)bxx * 64;
    const unsigned short* Ap = A + (long)bzz * sA;
    const unsigned short* Bp = Bm + (long)bzz * sB;
    const int epi = (epiPack >> (bzz * 4)) & 15;
    const int r8 = lane >> 3;
    const int cg = (lane & 7) ^ r8;          // swizzled global 16B-chunk

    const unsigned short* gA[4]; const unsigned short* gB[2];
    unsigned short* lA[4]; unsigned short* lB[2];
    #pragma unroll
    for (int t = 0; t < 4; ++t) {
        int ch = w * 4 + t;
        gA[t] = Ap + (rowBase + ch * 8 + r8) * (long)K + cg * 8;
        lA[t] = &As[0][ch * 512];
    }
    #pragma unroll
    for (int t = 0; t < 2; ++t) {
        int ch = w * 2 + t;
        gB[t] = Bp + (colBase + ch * 8 + r8) * (long)K + cg * 8;
        lB[t] = &Bs[0][ch * 512];
    }

    f32x4 acc[4][2] = {};
    #pragma unroll
    for (int t = 0; t < 4; ++t) { load_lds16(gA[t], lA[t]); gA[t] += 64; }
    #pragma unroll
    for (int t = 0; t < 2; ++t) { load_lds16(gB[t], lB[t]); gB[t] += 64; }

    const int nIter = K >> 6;
    for (int it = 0; it < nIter; ++it) {
        const int cb = it & 1;
        if (it + 1 < nIter) {
            const int nb = cb ^ 1;
            #pragma unroll
            for (int t = 0; t < 4; ++t) { load_lds16(gA[t], lA[t] + nb * 8192); gA[t] += 64; }
            #pragma unroll
            for (int t = 0; t < 2; ++t) { load_lds16(gB[t], lB[t] + nb * 4096); gB[t] += 64; }
            __builtin_amdgcn_s_waitcnt(0xF76);   // vmcnt<=6
        } else {
            __builtin_amdgcn_s_waitcnt(0xF70);   // vmcnt(0)
        }
        raw_barrier();
        const unsigned short* Ac = As[cb];
        const unsigned short* Bc = Bs[cb];
        #pragma unroll
        for (int ks = 0; ks < 2; ++ks) {
            const int cl = ((ks * 4 + quad) ^ (l16 & 7)) * 8;
            bf16x8 af[4], bfr[2];
            #pragma unroll
            for (int i = 0; i < 4; ++i)
                af[i] = *(const bf16x8*)&Ac[(wr + i * 16 + l16) * 64 + cl];
            #pragma unroll
            for (int j = 0; j < 2; ++j)
                bfr[j] = *(const bf16x8*)&Bc[(wc + j * 16 + l16) * 64 + cl];
            #pragma unroll
            for (int i = 0; i < 4; ++i)
                #pragma unroll
                for (int j = 0; j < 2; ++j)
                    acc[i][j] = __builtin_amdgcn_mfma_f32_16x16x32_bf16(af[i], bfr[j], acc[i][j], 0, 0, 0);
        }
        raw_barrier();
    }

    char* Cb = (char*)Cv + (long)bzz * sCb;
    float* Cf = (float*)Cb;
    unsigned short* Ch = (unsigned short*)Cb;
    const long zel = (long)bzz * (sCb >> 2);
    const float* r1z = r1 + zel;
    const float* r2z = r2 + zel;
    unsigned short* qhz = qh + zel;
    #pragma unroll
    for (int i = 0; i < 4; ++i)
        #pragma unroll
        for (int r = 0; r < 4; ++r) {
            long gr = rowBase + wr + i * 16 + quad * 4 + r;
            #pragma unroll
            for (int j = 0; j < 2; ++j) {
                long gc = colBase + wc + j * 16 + l16;
                epi_store(epi, Cf, Ch, gr * (long)Mc + gc, (int)gc, acc[i][j][r],
                          gbp, r1z, r2z, qhz);
            }
        }
}

// ---------------- NT GEMM 256xBN tile, 8-phase pipelined (big GEMMs) ------
// 512 thr = 8 waves (2M x 4N), wave tile 128 x BN/4, BK=64.
// LDS: 2 dbuf x (A 256x64 + B BNx64) bf16, chunk-XOR swizzle.
// Per K-tile: 4 phases {ds_read subtile || stage -> barrier ->
// setprio(1) MFMA setprio(0) -> barrier}. A of t+1 staged ph0/1; B of t+2
// staged ph2/3; counted vmcnt(LB) at ph3 only.
#define P8_RD_A(p)                                                              \
    _Pragma("unroll") for (int fr = 0; fr < 2; ++fr)                            \
    _Pragma("unroll") for (int ks = 0; ks < 2; ++ks)                            \
        af[fr][ks] = *(const bf16x8*)&Ac[(wr + ((p) * 2 + fr) * 16 + l16) * 64  \
                                         + ((ks * 4 + quad) ^ (l16 & 7)) * 8];
#define P8_MFMA(p)                                                              \
    __builtin_amdgcn_s_setprio(1);                                              \
    _Pragma("unroll") for (int ks = 0; ks < 2; ++ks)                            \
    _Pragma("unroll") for (int fr = 0; fr < 2; ++fr)                            \
    _Pragma("unroll") for (int fc = 0; fc < FC; ++fc)                           \
        acc[(p) * 2 + fr][fc] = __builtin_amdgcn_mfma_f32_16x16x32_bf16(        \
            af[fr][ks], bfr[fc][ks], acc[(p) * 2 + fr][fc], 0, 0, 0);           \
    __builtin_amdgcn_s_setprio(0);
#define P8_STG_A(h)                                                             \
    do { load_lds16(gA[h][0], &Anx[lofsA[h][0]]); gA[h][0] += 64;               \
         load_lds16(gA[h][1], &Anx[lofsA[h][1]]); gA[h][1] += 64; } while (0)
#define P8_STG_B(j)                                                             \
    do { load_lds16(gB[j], &Bnx[lofsB[j]]); gB[j] += 64; } while (0)

template <int BN>
__global__ __launch_bounds__(512, 2) void gemm_nt_8p(
    const unsigned short* __restrict__ A, const unsigned short* __restrict__ Bm,
    void* __restrict__ Cv, int Mc, int K, long sA, long sB, long sCb, int epiPack,
    const unsigned short* __restrict__ rh)
{
    constexpr int LB = BN / 64;          // B loads per K-tile
    constexpr int FC = BN / 64;          // B frags per wave
    constexpr int WN = BN / 4;           // wave col span
    __shared__ unsigned short As[2][16384];
    __shared__ unsigned short Bs[2][BN * 64];
    int bx, by, bz; swz_bid(bx, by, bz);
    const int tid = threadIdx.x, lane = tid & 63, w = tid >> 6;   // 8 waves
    const int l16 = lane & 15, quad = lane >> 4;
    const int wr = (w >> 2) * 128, wc = (w & 3) * WN;
    const long rowBase = (long)by * 256;
    const long colBase = (long)bx * BN;
    const unsigned short* Ap = A + (long)bz * sA;
    const unsigned short* Bp = Bm + (long)bz * sB;
    const int epi = (epiPack >> (bz * 4)) & 15;
    const int r8 = lane >> 3;
    const int cg = (lane & 7) ^ r8;

    const unsigned short* gA[2][2];
    int lofsA[2][2];
    #pragma unroll
    for (int h = 0; h < 2; ++h)
        #pragma unroll
        for (int j = 0; j < 2; ++j) {
            const int rowOff = h * 128 + j * 64 + w * 8 + r8;
            gA[h][j] = Ap + (rowBase + rowOff) * (long)K + cg * 8;
            lofsA[h][j] = (h * 128 + j * 64 + w * 8) * 64;       // shorts
        }
    const unsigned short* gB[LB];
    int lofsB[LB];
    #pragma unroll
    for (int j = 0; j < LB; ++j) {
        const int rowOff = j * 64 + w * 8 + r8;
        gB[j] = Bp + (colBase + rowOff) * (long)K + cg * 8;
        lofsB[j] = (j * 64 + w * 8) * 64;
    }

    const int nT = K >> 6;
    f32x4 acc[8][FC] = {};

    // prologue: stage t0.A, t0.B, t1.B; A ptrs -> t1, B ptrs -> t2
    #pragma unroll
    for (int h = 0; h < 2; ++h)
        #pragma unroll
        for (int j = 0; j < 2; ++j) { load_lds16(gA[h][j], &As[0][lofsA[h][j]]); gA[h][j] += 64; }
    #pragma unroll
    for (int j = 0; j < LB; ++j) { load_lds16(gB[j], &Bs[0][lofsB[j]]); gB[j] += 64; }
    if (nT > 1) {
        #pragma unroll
        for (int j = 0; j < LB; ++j) { load_lds16(gB[j], &Bs[1][lofsB[j]]); gB[j] += 64; }
        __builtin_amdgcn_s_waitcnt(0x0F70 | LB);  // t0 landed; t1.B may fly
    } else {
        __builtin_amdgcn_s_waitcnt(0x0F70);
    }
    raw_barrier();

    for (int t = 0; t < nT; ++t) {
        const int cb = t & 1;
        const unsigned short* Ac = As[cb];
        const unsigned short* Bc = Bs[cb];
        unsigned short* Anx = As[cb ^ 1];    // tile t+1
        unsigned short* Bnx = Bs[cb];        // tile t+2 (same parity)
        const bool stA = (t + 1 < nT);
        const bool stB = (t + 2 < nT);
        bf16x8 bfr[FC][2];
        bf16x8 af[2][2];

        // phase 0: all B frags + A rows 0/1; stage A-half0 of t+1
        #pragma unroll
        for (int fc = 0; fc < FC; ++fc)
            #pragma unroll
            for (int ks = 0; ks < 2; ++ks)
                bfr[fc][ks] = *(const bf16x8*)&Bc[(wc + fc * 16 + l16) * 64
                                                 + ((ks * 4 + quad) ^ (l16 & 7)) * 8];
        P8_RD_A(0)
        if (stA) P8_STG_A(0);
        raw_barrier();
        P8_MFMA(0)
        raw_barrier();

        // phase 1: A rows 2/3; stage A-half1 of t+1
        P8_RD_A(1)
        if (stA) P8_STG_A(1);
        raw_barrier();
        P8_MFMA(1)
        raw_barrier();

        // phase 2: A rows 4/5; stage first half of B(t+2)
        P8_RD_A(2)
        if (stB) {
            #pragma unroll
            for (int j = 0; j < (LB + 1) / 2; ++j) P8_STG_B(j);
        }
        raw_barrier();
        P8_MFMA(2)
        raw_barrier();

        // phase 3: A rows 6/7; stage rest of B(t+2); counted vmcnt
        P8_RD_A(3)
        if (stB) {
            #pragma unroll
            for (int j = (LB + 1) / 2; j < LB; ++j) P8_STG_B(j);
            __builtin_amdgcn_s_waitcnt(0x0F70 | LB);  // t+1 landed; t+2.B may fly
        } else {
            __builtin_amdgcn_s_waitcnt(0x0F70);       // tail: drain
        }
        raw_barrier();
        P8_MFMA(3)
        raw_barrier();
    }

    char* Cb = (char*)Cv + (long)bz * sCb;
    float* Cf = (float*)Cb;
    unsigned short* Ch = (unsigned short*)Cb;
    #pragma unroll
    for (int i = 0; i < 8; ++i)
        #pragma unroll
        for (int r = 0; r < 4; ++r) {
            long gr = rowBase + wr + i * 16 + quad * 4 + r;
            #pragma unroll
            for (int j = 0; j < FC; ++j) {
                long gc = colBase + wc + j * 16 + l16;
                long off = gr * (long)Mc + gc;
                float v = acc[i][j][r];
                if (epi == 0)      Cf[off] = v;
                else if (epi == 2) Ch[off] = f2bf(v);
                else if (epi == 3) Ch[off] = f2bf(silu(v));
                else               Ch[off] = f2bf(bf2f(rh[off]) - v);   // epi 7: err
            }
        }
}

// ---------------- tiled transpose (+convert) to bf16, batched via z
template <typename TS>
__global__ void k_transpose(const TS* __restrict__ src, unsigned short* __restrict__ dst,
                            int R, int C, int dstLd, int dstOff, long sSrc, long sDst)
{
    __shared__ float tile[32][33];
    const TS* sp = src + (long)blockIdx.z * sSrc;
    unsigned short* dp = dst + (long)blockIdx.z * sDst;
    int c0 = blockIdx.x * 32, r0 = blockIdx.y * 32;
    int tx = threadIdx.x, ty = threadIdx.y;     // 32 x 8
    #pragma unroll
    for (int i = 0; i < 4; ++i)
        tile[ty + i * 8][tx] = ldf(&sp[(long)(r0 + ty + i * 8) * C + c0 + tx]);
    __syncthreads();
    #pragma unroll
    for (int i = 0; i < 4; ++i)
        dp[(long)(c0 + ty + i * 8) * dstLd + dstOff + r0 + tx] = f2bf(tile[tx][ty + i * 8]);
}

// z0: eT[m][n] = errN[n][m]; z1: kT[m][n] = k_bf[n][m]  (both bf16)
__global__ void k_errT_kT(const unsigned short* __restrict__ errN,
                          const unsigned short* __restrict__ k_bf, unsigned short* __restrict__ eT)
{
    __shared__ float tile[32][33];
    int z = blockIdx.z;
    const unsigned short* src = (z == 0) ? errN : k_bf;
    int c0 = blockIdx.x * 32, r0 = blockIdx.y * 32;
    int tx = threadIdx.x, ty = threadIdx.y;
    #pragma unroll
    for (int i = 0; i < 4; ++i) {
        long idx = (long)(r0 + ty + i * 8) * MD + c0 + tx;
        tile[ty + i * 8][tx] = bf2f(src[idx]);
    }
    __syncthreads();
    unsigned short* dst = eT + (long)z * NM;
    #pragma unroll
    for (int i = 0; i < 4; ++i)
        dst[(long)(c0 + ty + i * 8) * MD + r0 + tx] = f2bf(tile[tx][ty + i * 8]);
}

// snapT[h][d] = bf16((1-a)*mem[d][h] + eta*sur[d][h] + (theta/2048)*momT[h][d])
__global__ void k_snapT(const float* __restrict__ mem, const float* __restrict__ sur,
                        const float* __restrict__ momT, const float* __restrict__ scal,
                        unsigned short* __restrict__ dst)
{
    __shared__ float tile[32][33];
    float eta = scal[0], theta = scal[1], alpha = scal[2];
    int h0 = blockIdx.y * 32, d0 = blockIdx.x * 32;
    int tx = threadIdx.x, ty = threadIdx.y;
    #pragma unroll
    for (int i = 0; i < 4; ++i) {
        long idx = (long)(d0 + ty + i * 8) * MD + h0 + tx;
        tile[ty + i * 8][tx] = (1.f - alpha) * mem[idx] + eta * sur[idx];
    }
    __syncthreads();
    #pragma unroll
    for (int i = 0; i < 4; ++i) {
        long oidx = (long)(h0 + ty + i * 8) * MD + d0 + tx;
        dst[oidx] = f2bf(tile[tx][ty + i * 8] + theta * (1.f / 2048.f) * momT[oidx]);
    }
}

// ---------------- fused / vectorized elementwise ----------------
__global__ void k_cvt_multi(const float* s0, const float* s1, const float* s2, const float* s3,
                            const float* s4, const float* s5, const float* s6, const float* s7,
                            unsigned short* d0, unsigned short* d1, unsigned short* d2, unsigned short* d3,
                            unsigned short* d4, unsigned short* d5, unsigned short* d6, unsigned short* d7)
{
    int seg = blockIdx.x >> 11;
    const float* s; unsigned short* d;
    switch (seg) {
        case 0: s = s0; d = d0; break;  case 1: s = s1; d = d1; break;
        case 2: s = s2; d = d2; break;  case 3: s = s3; d = d3; break;
        case 4: s = s4; d = d4; break;  case 5: s = s5; d = d5; break;
        case 6: s = s6; d = d6; break;  default: s = s7; d = d7; break;
    }
    long idx = ((long)(blockIdx.x & 2047) * 256 + threadIdx.x) * 8;
    float4 a = *(const float4*)(s + idx);
    float4 b = *(const float4*)(s + idx + 4);
    u16x8 o;
    o[0] = f2bf(a.x); o[1] = f2bf(a.y); o[2] = f2bf(a.z); o[3] = f2bf(a.w);
    o[4] = f2bf(b.x); o[5] = f2bf(b.y); o[6] = f2bf(b.z); o[7] = f2bf(b.w);
    *(u16x8*)(d + idx) = o;
}

// depthwise causal conv z3, vec8. tproj: [2048][6144] bf16; conv: [3][2048][2048]
__global__ void k_dwconv(const unsigned short* __restrict__ tproj,
                         const float* __restrict__ qdw, const float* __restrict__ kdw,
                         const float* __restrict__ vdw, unsigned short* __restrict__ conv)
{
    long u = (long)blockIdx.x * 256 + threadIdx.x;
    long flat = u * 8;
    int z = (int)(flat >> 22);
    int rem = (int)(flat & (NM - 1));
    int n = rem >> 11, m = rem & 2047;
    int l = n & 1023;
    const float* dw = (z == 0) ? qdw : (z == 1) ? kdw : vdw;
    const unsigned short* src = tproj + (long)n * 6144 + z * 2048 + m;
    float4 dwv[8];
    #pragma unroll
    for (int e = 0; e < 8; ++e) dwv[e] = *(const float4*)(dw + (m + e) * 4);
    float acc[8] = {};
    #pragma unroll
    for (int j = 0; j < 4; ++j) {
        int dl = j - 3;
        if (l + dl >= 0) {
            u16x8 r = *(const u16x8*)(src + (long)dl * 6144);
            #pragma unroll
            for (int e = 0; e < 8; ++e)
                acc[e] += ((const float*)&dwv[e])[j] * bf2f(r[e]);
        }
    }
    u16x8 o;
    #pragma unroll
    for (int e = 0; e < 8; ++e) o[e] = f2bf(acc[e]);
    *(u16x8*)(conv + (long)z * NM + (long)n * 2048 + m) = o;
}

// post-pointwise on silu'd bf16 rows: z0: l2n -> q_bf ; z1: l2n -> k_bf + kwp
__global__ void k_post_qkv(const unsigned short* __restrict__ tbf, unsigned short* __restrict__ q_bf,
                           unsigned short* __restrict__ k_bf, unsigned short* __restrict__ kwp)
{
    int bid = blockIdx.x, z = bid >> 11, n = bid & 2047;
    const unsigned short* row = tbf + (long)z * NM + (long)n * 2048;
    int t = threadIdx.x;
    u16x8 iv = *(const u16x8*)(row + t * 8);
    float v[8];
    #pragma unroll
    for (int e = 0; e < 8; ++e) v[e] = bf2f(iv[e]);
    float ss = 0.f;
    #pragma unroll
    for (int e = 0; e < 8; ++e) ss += v[e] * v[e];
    ss = block_reduce_sum(ss);
    float inv = 1.f / (sqrtf(ss) + 1e-6f);
    u16x8 o;
    #pragma unroll
    for (int e = 0; e < 8; ++e) o[e] = f2bf(v[e] * inv);
    if (z == 0) {
        *(u16x8*)(q_bf + (long)n * 2048 + t * 8) = o;
    } else {
        *(u16x8*)(k_bf + (long)n * 2048 + t * 8) = o;
        int bb = n >> 10, l = n & 1023;
        *(u16x8*)(kwp + ((long)bb * PLP + 8 + l) * MD + t * 8) = o;
    }
}

// misc: pkn rows (8) | pv->vwpT (64) | kwp tail zero (240) | vwpT tail zero (240)
__global__ void k_misc(const float* __restrict__ pk, const float* __restrict__ pv,
                       unsigned short* __restrict__ kwp, unsigned short* __restrict__ vwpT)
{
    int bid = blockIdx.x, t = threadIdx.x;
    if (bid < 8) {
        const float* row = pk + bid * MD;
        float4 a = *(const float4*)(row + t * 8);
        float4 b = *(const float4*)(row + t * 8 + 4);
        float v[8] = {a.x, a.y, a.z, a.w, b.x, b.y, b.z, b.w};
        float ss = 0.f;
        #pragma unroll
        for (int e = 0; e < 8; ++e) ss += v[e] * v[e];
        ss = block_reduce_sum(ss);
        float inv = 1.f / (sqrtf(ss) + 1e-6f);
        u16x8 o;
        #pragma unroll
        for (int e = 0; e < 8; ++e) o[e] = f2bf(v[e] * inv);
        *(u16x8*)(kwp + (long)bid * MD + t * 8) = o;
        *(u16x8*)(kwp + (long)PLP * MD + (long)bid * MD + t * 8) = o;
    } else if (bid < 72) {
        int i = (bid - 8) * 256 + t;         // 16384 = 2048*8
        int m = i >> 3, pp = i & 7;
        unsigned short h = f2bf(pv[pp * MD + m]);
        vwpT[(long)m * PLP + pp] = h;
        vwpT[(long)MD * PLP + (long)m * PLP + pp] = h;
    } else if (bid < 312) {
        long flat = ((long)(bid - 72) * 256 + t) * 8;    // 2*120*2048
        int b = (int)(flat / 245760);
        int r = (int)(flat % 245760);
        int j = 1032 + (r >> 11), m = r & 2047;
        u16x8 zz = {};
        *(u16x8*)(kwp + ((long)b * PLP + j) * MD + m) = zz;
    } else {
        long flat = ((long)(bid - 312) * 256 + t) * 8;   // 2*2048*120
        int bm = (int)(flat / 120);
        int o = (int)(flat % 120);
        u16x8 zz = {};
        *(u16x8*)(vwpT + (long)bm * PLP + 1032 + o) = zz;
    }
}

// pooled dots (eta/theta/alpha) + x -> bf16 convert, fused (x read once)
__global__ void k_pooled(const float* __restrict__ x, const float* __restrict__ ew,
                         const float* __restrict__ tw, const float* __restrict__ aw,
                         float* __restrict__ dots, unsigned short* __restrict__ xbf) {
    int b = blockIdx.y;
    long flat = ((long)blockIdx.x * 256 + threadIdx.x) * 8;   // [0, 2M) per b
    long gi = (long)b * 1024 * MD + flat;
    int d = (int)(flat & (MD - 1));
    float4 a = *(const float4*)(x + gi);
    float4 b4 = *(const float4*)(x + gi + 4);
    float xv[8] = {a.x, a.y, a.z, a.w, b4.x, b4.y, b4.z, b4.w};
    float4 e0 = *(const float4*)(ew + d), e1 = *(const float4*)(ew + d + 4);
    float4 t0 = *(const float4*)(tw + d), t1 = *(const float4*)(tw + d + 4);
    float4 w0 = *(const float4*)(aw + d), w1 = *(const float4*)(aw + d + 4);
    u16x8 o;
    #pragma unroll
    for (int e = 0; e < 8; ++e) o[e] = f2bf(xv[e]);
    *(u16x8*)(xbf + gi) = o;
    float s0 = xv[0]*e0.x + xv[1]*e0.y + xv[2]*e0.z + xv[3]*e0.w
             + xv[4]*e1.x + xv[5]*e1.y + xv[6]*e1.z + xv[7]*e1.w;
    float s1 = xv[0]*t0.x + xv[1]*t0.y + xv[2]*t0.z + xv[3]*t0.w
             + xv[4]*t1.x + xv[5]*t1.y + xv[6]*t1.z + xv[7]*t1.w;
    float s2 = xv[0]*w0.x + xv[1]*w0.y + xv[2]*w0.z + xv[3]*w0.w
             + xv[4]*w1.x + xv[5]*w1.y + xv[6]*w1.z + xv[7]*w1.w;
    s0 = block_reduce_sum(s0);
    if (threadIdx.x == 0) atomicAdd(&dots[0 + b], s0);
    s1 = block_reduce_sum(s1);
    if (threadIdx.x == 0) atomicAdd(&dots[2 + b], s1);
    s2 = block_reduce_sum(s2);
    if (threadIdx.x == 0) atomicAdd(&dots[4 + b], s2);
}
__global__ void k_scal_fin(const float* __restrict__ dots, const float* __restrict__ eb,
                           const float* __restrict__ tb, const float* __restrict__ ab,
                           float* __restrict__ scal) {
    if (threadIdx.x == 0 && blockIdx.x == 0) {
        const float invL = 1.f / 1024.f;
        float e = 0, th = 0, al = 0;
        for (int b = 0; b < 2; ++b) {
            e  += sigm(dots[0 + b] * invL + eb[0]);
            th += sigm(dots[2 + b] * invL + tb[0]);
            al += sigm(dots[4 + b] * invL + ab[0]);
        }
        scal[0] = e * 0.5f; scal[1] = th * 0.5f; scal[2] = al * 0.5f;
    }
}

__global__ void k_softmax(const float* __restrict__ S, unsigned short* __restrict__ attn) {
    int l = blockIdx.x, b = blockIdx.y;
    long base = ((long)b * 1024 + l) * PLP;
    int nvis = 8 + l + 1;
    const float scale = 0.022097086912079608f;  // 1/sqrt(2048)
    int t = threadIdx.x;
    float vals[5];
    float mx = -1e30f;
    #pragma unroll
    for (int s = 0; s < 5; ++s) {
        int j = t + s * 256;
        float v = -1e30f;
        if (j < nvis) v = S[base + j] * scale;
        vals[s] = v;
        mx = fmaxf(mx, v);
    }
    mx = block_reduce_max(mx);
    float sum = 0.f;
    #pragma unroll
    for (int s = 0; s < 5; ++s) {
        int j = t + s * 256;
        float e = 0.f;
        if (j < nvis) e = __expf(vals[s] - mx);
        vals[s] = e; sum += e;
    }
    sum = block_reduce_sum(sum);
    float inv = 1.f / sum;
    #pragma unroll
    for (int s = 0; s < 5; ++s) {
        int j = t + s * 256;
        if (j < PLP) attn[base + j] = f2bf(vals[s] * inv);
    }
}

__global__ void k_final(const float* __restrict__ x, const float* __restrict__ y,
                        const float* __restrict__ lnw, float* __restrict__ out) {
    int n = blockIdx.x;
    long base = (long)n * MD;
    int t = threadIdx.x;
    float4 a0 = *(const float4*)(x + base + t * 8), a1 = *(const float4*)(x + base + t * 8 + 4);
    float4 b0 = *(const float4*)(y + base + t * 8), b1 = *(const float4*)(y + base + t * 8 + 4);
    float v[8] = {a0.x + b0.x, a0.y + b0.y, a0.z + b0.z, a0.w + b0.w,
                  a1.x + b1.x, a1.y + b1.y, a1.z + b1.z, a1.w + b1.w};
    float ss = 0.f;
    #pragma unroll
    for (int e = 0; e < 8; ++e) ss += v[e] * v[e];
    ss = block_reduce_sum(ss);
    float inv = rsqrtf(ss * (1.f / 2048.f) + 1e-6f);
    float4 w0 = *(const float4*)(lnw + t * 8), w1 = *(const float4*)(lnw + t * 8 + 4);
    float4 o0 = {v[0] * inv * w0.x, v[1] * inv * w0.y, v[2] * inv * w0.z, v[3] * inv * w0.w};
    float4 o1 = {v[4] * inv * w1.x, v[5] * inv * w1.y, v[6] * inv * w1.z, v[7] * inv * w1.w};
    *(float4*)(out + base + t * 8) = o0;
    *(float4*)(out + base + t * 8 + 4) = o1;
}

// ---------------- host-side ----------------
static inline void gemm64(hipStream_t st, const void* A, const void* B, void* C,
                          int Mc, int K, long sA, long sB, long sCb,
                          int gx, int gy, int gz, int epiPack,
                          const float* gbp = nullptr, const float* r1 = nullptr,
                          const float* r2 = nullptr, unsigned short* qh = nullptr) {
    hipLaunchKernelGGL(gemm_nt, dim3(gx, gy, gz), dim3(256), 0, st,
                       (const unsigned short*)A, (const unsigned short*)B, C,
                       Mc, K, sA, sB, sCb, epiPack, gbp, r1, r2, qh);
}
template <int BN>
static inline void gemm8p(hipStream_t st, const void* A, const void* B, void* C,
                          int Mc, int K, long sA, long sB, long sCb,
                          int gx, int gy, int gz, int epiPack,
                          const unsigned short* rh = nullptr) {
    hipLaunchKernelGGL(gemm_nt_8p<BN>, dim3(gx, gy, gz), dim3(512), 0, st,
                       (const unsigned short*)A, (const unsigned short*)B, C,
                       Mc, K, sA, sB, sCb, epiPack, rh);
}

extern "C" void kernel_launch(void* const* d_in, const int* in_sizes, int n_in,
                              void* d_out, int out_size, void* d_ws, size_t ws_size,
                              hipStream_t stream) {
    const float* x    = (const float*)d_in[0];
    const float* Wq   = (const float*)d_in[1];
    const float* Wk   = (const float*)d_in[2];
    const float* Wv   = (const float*)d_in[3];
    const float* qdw  = (const float*)d_in[4];
    const float* kdw  = (const float*)d_in[5];
    const float* vdw  = (const float*)d_in[6];
    const float* qpw  = (const float*)d_in[7];
    const float* kpw  = (const float*)d_in[8];
    const float* vpw  = (const float*)d_in[9];
    const float* pk   = (const float*)d_in[10];
    const float* pv   = (const float*)d_in[11];
    const float* mw1  = (const float*)d_in[12];
    const float* mw2  = (const float*)d_in[13];
    const float* etaw = (const float*)d_in[14];
    const float* etab = (const float*)d_in[15];
    const float* thw  = (const float*)d_in[16];
    const float* thb  = (const float*)d_in[17];
    const float* alw  = (const float*)d_in[18];
    const float* alb  = (const float*)d_in[19];
    const float* gw   = (const float*)d_in[20];
    const float* gb   = (const float*)d_in[21];
    const float* ow   = (const float*)d_in[22];
    const float* lnw  = (const float*)d_in[23];
    const float* mem  = (const float*)d_in[24];
    const float* sur  = (const float*)d_in[25];
    float* out = (float*)d_out;

    char* ws = (char*)d_ws;
    const size_t MB = 1024 * 1024;
    float* dots = (float*)ws;
    float* scal = (float*)(ws + 1024);
    // memory map (160 MB + 4 KB):
    float*          t0f  = (float*)(ws + 4096);                 // 48MB region A
    float*          t1f  = t0f + NM;
    float*          t2f  = t0f + 2 * NM;
    unsigned short* tproj = (unsigned short*)t0f;               // overlays (24MB)
    unsigned short* t_bf  = (unsigned short*)t0f;               // G2 silu'd bf16 [3][NM]
    unsigned short* vf    = t_bf + 2 * (long)NM;                // z2 slice == vf
    float*          retf = (float*)(ws + 4096 + 48 * MB);       // 16MB
    unsigned short* k_bf = (unsigned short*)(ws + 4096 + 64 * MB);  // 8MB
    unsigned short* q_bf = k_bf + NM;                               // 8MB
    unsigned short* qc   = k_bf + 2 * NM;                           // 8MB (silu(mlp1), later rg)
    unsigned short* g_bf = k_bf;                                    // reuse after errT/kT
    unsigned short* x_bf = (unsigned short*)(ws + 4096 + 88 * MB);  // 8MB (later errN, attn)
    unsigned short* errN = x_bf;
    unsigned short* attn = x_bf;
    unsigned short* wQKV = (unsigned short*)(ws + 4096 + 96 * MB);  // 24MB region E
    unsigned short* conv = wQKV;
    unsigned short* kwp  = wQKV;
    unsigned short* vwpT = kwp + (long)2 * PLP * MD;
    unsigned short* wPW  = (unsigned short*)(ws + 4096 + 120 * MB); // 24MB region F
    unsigned short* eT   = wPW;
    unsigned short* kT   = eT + NM;
    unsigned short* gw_bf = wPW;
    unsigned short* ow_bf = wPW + NM;
    unsigned short* wMem  = (unsigned short*)(ws + 4096 + 144 * MB); // 16MB region G
    unsigned short* wMlp1 = wMem + NM;
    unsigned short* wSnap = wMem;
    unsigned short* wMlp2 = wMem + NM;

    const dim3 b256(256);
    const dim3 bT(32, 8);

    // 1. scalars + x -> bf16 (fused)
    hipMemsetAsync(dots, 0, 256, stream);
    hipLaunchKernelGGL(k_pooled, dim3(1024, 2), b256, 0, stream, x, etaw, thw, alw, dots, x_bf);
    hipLaunchKernelGGL(k_scal_fin, dim3(1), dim3(64), 0, stream, dots, etab, thb, alb, scal);
    // 2. converts: Wq, Wk, Wv, qpw, kpw, vpw, mw1 (7 segs)
    hipLaunchKernelGGL(k_cvt_multi, dim3(14336), b256, 0, stream,
                       Wq, Wk, Wv, qpw, kpw, vpw, mw1, mw1,
                       wQKV, wQKV + NM, wQKV + 2 * (long)NM,
                       wPW, wPW + NM, wPW + 2 * (long)NM, wMlp1, wMlp1);
    // 3. mem -> wMem (transposed bf16)
    hipLaunchKernelGGL(k_transpose<float>, dim3(64, 64, 1), bT, 0, stream,
                       mem, wMem, MD, MD, MD, 0, 0L, 0L);
    // 4. G1 (BN=192, grid 256): wide qkv projection -> tproj bf16 [2048][6144]
    gemm8p<192>(stream, x_bf, wQKV, tproj, 6144, MD, 0, 0, 0, 32, 8, 1, 0x2);
    // 5. depthwise conv z3 -> conv
    hipLaunchKernelGGL(k_dwconv, dim3(6144), b256, 0, stream, tproj, qdw, kdw, vdw, conv);
    // 6. G2 (BN=256): pointwise z3 -> silu'd bf16 t_bf (z2 == vf, no copy)
    gemm8p<256>(stream, conv, wPW, t_bf, MD, MD, NM, NM, (long)NM * 2, 8, 8, 3, 0x333);
    // 7. misc (kwp p-rows, vwpT p-cols, zero tails)
    hipLaunchKernelGGL(k_misc, dim3(552), b256, 0, stream, pk, pv, kwp, vwpT);
    // 8. post qkv (z0/z1): l2n -> q_bf, k_bf(+kwp)
    hipLaunchKernelGGL(k_post_qkv, dim3(4096), b256, 0, stream, t_bf, q_bf, k_bf, kwp);
    // 9. vf -> vwpT (transposed, offset 8)
    hipLaunchKernelGGL(k_transpose<unsigned short>, dim3(64, 32, 2), bT, 0, stream,
                       vf, vwpT, 1024, MD, PLP, 8, (long)1024 * MD, (long)MD * PLP);
    // 10. G3 (BN=128, grid 256) z2: errN = bf16(vf - k.memT) ; mlp1 -> silu bf16 -> qc
    gemm8p<128>(stream, k_bf, wMem, errN, MD, MD, NM, NM,
                (long)((char*)qc - (char*)errN), 16, 8, 2, 0x37, vf);
    // 11. errT / kT (bf16 transposes)
    hipLaunchKernelGGL(k_errT_kT, dim3(64, 64, 2), bT, 0, stream, errN, k_bf, eT);
    // 12. G4: momT = eT.kT -> t2f
    gemm64(stream, eT, kT, t2f, MD, MD, 0, 0, 0, 32, 16, 1, 0);
    // 13. snapT -> wSnap
    hipLaunchKernelGGL(k_snapT, dim3(64, 64), bT, 0, stream, mem, sur, t2f, scal, wSnap);
    // 14. converts: mw2, gw, ow
    hipLaunchKernelGGL(k_cvt_multi, dim3(6144), b256, 0, stream,
                       mw2, gw, ow, mw2, mw2, mw2, mw2, mw2,
                       wMlp2, gw_bf, ow_bf, wMlp2, wMlp2, wMlp2, wMlp2, wMlp2);
    // 15. G5 (BN=128, grid 256) z2: linret = q.snapT -> retf ; mlp2 = qc.wMlp2 -> t1f
    gemm8p<128>(stream, q_bf, wSnap, retf, MD, MD, NM, NM,
                (long)((char*)t1f - (char*)retf), 16, 8, 2, 0x00);
    // 16. G6: scores z2 -> t2f
    gemm64(stream, q_bf, kwp, t2f, PLP, MD,
           (long)1024 * MD, (long)PLP * MD, (long)1024 * PLP * 4, 18, 8, 2, 0);
    // 17. softmax -> attn bf16
    hipLaunchKernelGGL(k_softmax, dim3(1024, 2), b256, 0, stream, t2f, attn);
    // 18. G7: context z2, epi5: retf += ctx AND qc = bf16(retf + mlp2)
    gemm64(stream, attn, vwpT, retf, MD, PLP,
           (long)1024 * PLP, (long)MD * PLP, (long)1024 * MD * 4, 32, 8, 2, 0x55,
           nullptr, retf, t1f, qc);
    // 19. G8 epi4: g_bf = bf16(sigm(rg.gwT + gb) * (retf + mlp2))
    gemm64(stream, qc, gw_bf, g_bf, MD, MD, 0, 0, 0, 32, 16, 1, 4,
           gb, retf, t1f, nullptr);
    // 20. G9: outproj = g.owT -> t0f
    gemm64(stream, g_bf, ow_bf, t0f, MD, MD, 0, 0, 0, 32, 16, 1, 0);
    // 21. final RMSNorm
    hipLaunchKernelGGL(k_final, dim3(2048), b256, 0, stream, x, t0f, lnw, out);
}

// Round 5
// 767.923 us; speedup vs baseline: 1.1204x; 1.1204x over previous
//
#include <hip/hip_runtime.h>
#include <hip/hip_bf16.h>

// ---------------------------------------------------------------------------
// TitansMemory: B=2, L=1024, D=M=2048, P=8, Kconv=4.
// bf16 NT-GEMM. G1/G2: 256x256 8-phase pipelined (192-block grids, XCD swz);
// G3/G5: 128x128 2-barrier (512-block grids, full machine); small GEMMs
// 128x64. Epilogue fusion: G2 silu-bf16 (z2==vf), G3 err-bf16, G7 qc,
// G8 gate. k_pooled: atomic-free partial-sum reduction + fused x->bf16.
// ---------------------------------------------------------------------------

#define NROWS 2048      // B*L
#define MD    2048      // D == M
#define PL    1032      // P + L
#define PLP   1152      // padded
#define NM    4194304   // 2048*2048

using bf16x8 = __attribute__((ext_vector_type(8))) __bf16;
using f32x4  = __attribute__((ext_vector_type(4))) float;
using u16x8  = __attribute__((ext_vector_type(8))) unsigned short;

__device__ __forceinline__ unsigned short f2bf(float f) {
    union { float f; unsigned int u; } c; c.f = f;
    unsigned int u = c.u;
    return (unsigned short)((u + 0x7fffu + ((u >> 16) & 1u)) >> 16);
}
__device__ __forceinline__ float bf2f(unsigned short h) {
    union { float f; unsigned int u; } c; c.u = ((unsigned int)h) << 16;
    return c.f;
}
__device__ __forceinline__ float ldf(const float* p) { return *p; }
__device__ __forceinline__ float ldf(const unsigned short* p) { return bf2f(*p); }
__device__ __forceinline__ float sigm(float x) { return 1.f / (1.f + __expf(-x)); }
__device__ __forceinline__ float silu(float x) { return x / (1.f + __expf(-x)); }

__device__ __forceinline__ float block_reduce_sum(float v) {
    __shared__ float ws[4];
    #pragma unroll
    for (int o = 32; o > 0; o >>= 1) v += __shfl_down(v, o);
    __syncthreads();
    if ((threadIdx.x & 63) == 0) ws[threadIdx.x >> 6] = v;
    __syncthreads();
    return (ws[0] + ws[1]) + (ws[2] + ws[3]);
}
__device__ __forceinline__ float block_reduce_max(float v) {
    __shared__ float wm[4];
    #pragma unroll
    for (int o = 32; o > 0; o >>= 1) v = fmaxf(v, __shfl_down(v, o));
    __syncthreads();
    if ((threadIdx.x & 63) == 0) wm[threadIdx.x >> 6] = v;
    __syncthreads();
    return fmaxf(fmaxf(wm[0], wm[1]), fmaxf(wm[2], wm[3]));
}

__device__ __forceinline__ void load_lds16(const unsigned short* g, unsigned short* l) {
    __builtin_amdgcn_global_load_lds(
        (const __attribute__((address_space(1))) unsigned int*)g,
        (__attribute__((address_space(3))) unsigned int*)l, 16, 0, 0);
}
__device__ __forceinline__ void raw_barrier() {
    __asm__ volatile("" ::: "memory");
    __builtin_amdgcn_s_barrier();
    __asm__ volatile("" ::: "memory");
}
// T1: XCD-aware bijective block remap (8 XCDs). Only if nwg % 8 == 0.
__device__ __forceinline__ void swz_bid(int& bx, int& by, int& bz) {
    const int gx = gridDim.x, gy = gridDim.y, gz = gridDim.z;
    const int nwg = gx * gy * gz;
    int id = blockIdx.x + gx * (blockIdx.y + gy * blockIdx.z);
    if ((nwg & 7) == 0) { int c = nwg >> 3; id = (id & 7) * c + (id >> 3); }
    bx = id % gx; id /= gx; by = id % gy; bz = id / gy;
}
// epi codes: 0 f32-store, 1 f32-accum, 2 bf16, 3 silu->bf16,
// 4 gate: bf16(sigm(v+gb[gc]) * (r1[off]+r2[off]))          (G8)
// 5 ctx : r=Cf[off]+v; Cf[off]=r; qh[off]=bf16(r+r2[off])   (G7 + addcvt)
// 7 err : Ch[off] = bf16(bf2f(rh[off]) - v)                 (G3 z0)
__device__ __forceinline__ void epi_store(int epi, float* Cf, unsigned short* Ch,
                                          long off, int gc, float v,
                                          const float* gbp, const float* r1z,
                                          const float* r2z, unsigned short* qhz) {
    if (epi == 0)      Cf[off] = v;
    else if (epi == 1) Cf[off] += v;
    else if (epi == 2) Ch[off] = f2bf(v);
    else if (epi == 3) Ch[off] = f2bf(silu(v));
    else if (epi == 4) Ch[off] = f2bf(sigm(v + gbp[gc]) * (r1z[off] + r2z[off]));
    else { float r = Cf[off] + v; Cf[off] = r; qhz[off] = f2bf(r + r2z[off]); }
}

// ---------------- NT GEMM 128x64 tile (small/single GEMMs) ----------------
// C[n,m] = sum_k A[n,k]*B[m,k]. BK=64, dbuf, vmcnt(6) prefetch.
__global__ __launch_bounds__(256) void gemm_nt(
    const unsigned short* __restrict__ A, const unsigned short* __restrict__ Bm,
    void* __restrict__ Cv, int Mc, int K, long sA, long sB, long sCb, int epiPack,
    const float* __restrict__ gbp, const float* __restrict__ r1,
    const float* __restrict__ r2, unsigned short* __restrict__ qh)
{
    __shared__ unsigned short As[2][8192];
    __shared__ unsigned short Bs[2][4096];
    int bxx, byy, bzz; swz_bid(bxx, byy, bzz);
    const int tid = threadIdx.x, lane = tid & 63, w = tid >> 6;
    const int l16 = lane & 15, quad = lane >> 4;
    const int wr = (w >> 1) * 64, wc = (w & 1) * 32;
    const long rowBase = (long)byy * 128;
    const long colBase = (long)bxx * 64;
    const unsigned short* Ap = A + (long)bzz * sA;
    const unsigned short* Bp = Bm + (long)bzz * sB;
    const int epi = (epiPack >> (bzz * 4)) & 15;
    const int r8 = lane >> 3;
    const int cg = (lane & 7) ^ r8;          // swizzled global 16B-chunk

    const unsigned short* gA[4]; const unsigned short* gB[2];
    unsigned short* lA[4]; unsigned short* lB[2];
    #pragma unroll
    for (int t = 0; t < 4; ++t) {
        int ch = w * 4 + t;
        gA[t] = Ap + (rowBase + ch * 8 + r8) * (long)K + cg * 8;
        lA[t] = &As[0][ch * 512];
    }
    #pragma unroll
    for (int t = 0; t < 2; ++t) {
        int ch = w * 2 + t;
        gB[t] = Bp + (colBase + ch * 8 + r8) * (long)K + cg * 8;
        lB[t] = &Bs[0][ch * 512];
    }

    f32x4 acc[4][2] = {};
    #pragma unroll
    for (int t = 0; t < 4; ++t) { load_lds16(gA[t], lA[t]); gA[t] += 64; }
    #pragma unroll
    for (int t = 0; t < 2; ++t) { load_lds16(gB[t], lB[t]); gB[t] += 64; }

    const int nIter = K >> 6;
    for (int it = 0; it < nIter; ++it) {
        const int cb = it & 1;
        if (it + 1 < nIter) {
            const int nb = cb ^ 1;
            #pragma unroll
            for (int t = 0; t < 4; ++t) { load_lds16(gA[t], lA[t] + nb * 8192); gA[t] += 64; }
            #pragma unroll
            for (int t = 0; t < 2; ++t) { load_lds16(gB[t], lB[t] + nb * 4096); gB[t] += 64; }
            __builtin_amdgcn_s_waitcnt(0xF76);   // vmcnt<=6
        } else {
            __builtin_amdgcn_s_waitcnt(0xF70);   // vmcnt(0)
        }
        raw_barrier();
        const unsigned short* Ac = As[cb];
        const unsigned short* Bc = Bs[cb];
        #pragma unroll
        for (int ks = 0; ks < 2; ++ks) {
            const int cl = ((ks * 4 + quad) ^ (l16 & 7)) * 8;
            bf16x8 af[4], bfr[2];
            #pragma unroll
            for (int i = 0; i < 4; ++i)
                af[i] = *(const bf16x8*)&Ac[(wr + i * 16 + l16) * 64 + cl];
            #pragma unroll
            for (int j = 0; j < 2; ++j)
                bfr[j] = *(const bf16x8*)&Bc[(wc + j * 16 + l16) * 64 + cl];
            #pragma unroll
            for (int i = 0; i < 4; ++i)
                #pragma unroll
                for (int j = 0; j < 2; ++j)
                    acc[i][j] = __builtin_amdgcn_mfma_f32_16x16x32_bf16(af[i], bfr[j], acc[i][j], 0, 0, 0);
        }
        raw_barrier();
    }

    char* Cb = (char*)Cv + (long)bzz * sCb;
    float* Cf = (float*)Cb;
    unsigned short* Ch = (unsigned short*)Cb;
    const long zel = (long)bzz * (sCb >> 2);
    const float* r1z = r1 + zel;
    const float* r2z = r2 + zel;
    unsigned short* qhz = qh + zel;
    #pragma unroll
    for (int i = 0; i < 4; ++i)
        #pragma unroll
        for (int r = 0; r < 4; ++r) {
            long gr = rowBase + wr + i * 16 + quad * 4 + r;
            #pragma unroll
            for (int j = 0; j < 2; ++j) {
                long gc = colBase + wc + j * 16 + l16;
                epi_store(epi, Cf, Ch, gr * (long)Mc + gc, (int)gc, acc[i][j][r],
                          gbp, r1z, r2z, qhz);
            }
        }
}

// ---------------- NT GEMM 128x128 tile (batched big GEMMs, full machine) --
__global__ __launch_bounds__(256) void gemm_nt_big(
    const unsigned short* __restrict__ A, const unsigned short* __restrict__ Bm,
    void* __restrict__ Cv, int Mc, int K, long sA, long sB, long sCb, int epiPack,
    const unsigned short* __restrict__ rh)
{
    __shared__ unsigned short As[2][8192];
    __shared__ unsigned short Bs[2][8192];
    int bxx, byy, bzz; swz_bid(bxx, byy, bzz);
    const int tid = threadIdx.x, lane = tid & 63, w = tid >> 6;
    const int l16 = lane & 15, quad = lane >> 4;
    const int wr = (w >> 1) * 64, wc = (w & 1) * 64;
    const long rowBase = (long)byy * 128;
    const long colBase = (long)bxx * 128;
    const unsigned short* Ap = A + (long)bzz * sA;
    const unsigned short* Bp = Bm + (long)bzz * sB;
    const int epi = (epiPack >> (bzz * 4)) & 15;
    const int r8 = lane >> 3;
    const int cg = (lane & 7) ^ r8;

    const unsigned short* gA[4]; const unsigned short* gB[4];
    unsigned short* lA[4]; unsigned short* lB[4];
    #pragma unroll
    for (int t = 0; t < 4; ++t) {
        int ch = w * 4 + t;                  // 16 chunks of 8 rows
        gA[t] = Ap + (rowBase + ch * 8 + r8) * (long)K + cg * 8;
        lA[t] = &As[0][ch * 512];
        gB[t] = Bp + (colBase + ch * 8 + r8) * (long)K + cg * 8;
        lB[t] = &Bs[0][ch * 512];
    }

    f32x4 acc[4][4] = {};
    #pragma unroll
    for (int t = 0; t < 4; ++t) { load_lds16(gA[t], lA[t]); gA[t] += 64; }
    #pragma unroll
    for (int t = 0; t < 4; ++t) { load_lds16(gB[t], lB[t]); gB[t] += 64; }

    const int nIter = K >> 6;
    for (int it = 0; it < nIter; ++it) {
        const int cb = it & 1;
        if (it + 1 < nIter) {
            const int nb = cb ^ 1;
            #pragma unroll
            for (int t = 0; t < 4; ++t) { load_lds16(gA[t], lA[t] + nb * 8192); gA[t] += 64; }
            #pragma unroll
            for (int t = 0; t < 4; ++t) { load_lds16(gB[t], lB[t] + nb * 8192); gB[t] += 64; }
            __builtin_amdgcn_s_waitcnt(0xF78);   // vmcnt<=8
        } else {
            __builtin_amdgcn_s_waitcnt(0xF70);   // vmcnt(0)
        }
        raw_barrier();
        const unsigned short* Ac = As[cb];
        const unsigned short* Bc = Bs[cb];
        #pragma unroll
        for (int ks = 0; ks < 2; ++ks) {
            const int cl = ((ks * 4 + quad) ^ (l16 & 7)) * 8;
            bf16x8 af[4], bfr[4];
            #pragma unroll
            for (int i = 0; i < 4; ++i)
                af[i] = *(const bf16x8*)&Ac[(wr + i * 16 + l16) * 64 + cl];
            #pragma unroll
            for (int j = 0; j < 4; ++j)
                bfr[j] = *(const bf16x8*)&Bc[(wc + j * 16 + l16) * 64 + cl];
            #pragma unroll
            for (int i = 0; i < 4; ++i)
                #pragma unroll
                for (int j = 0; j < 4; ++j)
                    acc[i][j] = __builtin_amdgcn_mfma_f32_16x16x32_bf16(af[i], bfr[j], acc[i][j], 0, 0, 0);
        }
        raw_barrier();
    }

    char* Cb = (char*)Cv + (long)bzz * sCb;
    float* Cf = (float*)Cb;
    unsigned short* Ch = (unsigned short*)Cb;
    #pragma unroll
    for (int i = 0; i < 4; ++i)
        #pragma unroll
        for (int r = 0; r < 4; ++r) {
            long gr = rowBase + wr + i * 16 + quad * 4 + r;
            #pragma unroll
            for (int j = 0; j < 4; ++j) {
                long gc = colBase + wc + j * 16 + l16;
                long off = gr * (long)Mc + gc;
                float v = acc[i][j][r];
                if (epi == 0)      Cf[off] = v;
                else if (epi == 2) Ch[off] = f2bf(v);
                else if (epi == 3) Ch[off] = f2bf(silu(v));
                else               Ch[off] = f2bf(bf2f(rh[off]) - v);   // epi 7: err
            }
        }
}

// ---------------- NT GEMM 256xBN tile, 8-phase pipelined (G1/G2) ----------
#define P8_RD_A(p)                                                              \
    _Pragma("unroll") for (int fr = 0; fr < 2; ++fr)                            \
    _Pragma("unroll") for (int ks = 0; ks < 2; ++ks)                            \
        af[fr][ks] = *(const bf16x8*)&Ac[(wr + ((p) * 2 + fr) * 16 + l16) * 64  \
                                         + ((ks * 4 + quad) ^ (l16 & 7)) * 8];
#define P8_MFMA(p)                                                              \
    __builtin_amdgcn_s_setprio(1);                                              \
    _Pragma("unroll") for (int ks = 0; ks < 2; ++ks)                            \
    _Pragma("unroll") for (int fr = 0; fr < 2; ++fr)                            \
    _Pragma("unroll") for (int fc = 0; fc < FC; ++fc)                           \
        acc[(p) * 2 + fr][fc] = __builtin_amdgcn_mfma_f32_16x16x32_bf16(        \
            af[fr][ks], bfr[fc][ks], acc[(p) * 2 + fr][fc], 0, 0, 0);           \
    __builtin_amdgcn_s_setprio(0);
#define P8_STG_A(h)                                                             \
    do { load_lds16(gA[h][0], &Anx[lofsA[h][0]]); gA[h][0] += 64;               \
         load_lds16(gA[h][1], &Anx[lofsA[h][1]]); gA[h][1] += 64; } while (0)
#define P8_STG_B(j)                                                             \
    do { load_lds16(gB[j], &Bnx[lofsB[j]]); gB[j] += 64; } while (0)

template <int BN>
__global__ __launch_bounds__(512, 2) void gemm_nt_8p(
    const unsigned short* __restrict__ A, const unsigned short* __restrict__ Bm,
    void* __restrict__ Cv, int Mc, int K, long sA, long sB, long sCb, int epiPack,
    const unsigned short* __restrict__ rh)
{
    constexpr int LB = BN / 64;          // B loads per K-tile
    constexpr int FC = BN / 64;          // B frags per wave
    constexpr int WN = BN / 4;           // wave col span
    __shared__ unsigned short As[2][16384];
    __shared__ unsigned short Bs[2][BN * 64];
    int bx, by, bz; swz_bid(bx, by, bz);
    const int tid = threadIdx.x, lane = tid & 63, w = tid >> 6;   // 8 waves
    const int l16 = lane & 15, quad = lane >> 4;
    const int wr = (w >> 2) * 128, wc = (w & 3) * WN;
    const long rowBase = (long)by * 256;
    const long colBase = (long)bx * BN;
    const unsigned short* Ap = A + (long)bz * sA;
    const unsigned short* Bp = Bm + (long)bz * sB;
    const int epi = (epiPack >> (bz * 4)) & 15;
    const int r8 = lane >> 3;
    const int cg = (lane & 7) ^ r8;

    const unsigned short* gA[2][2];
    int lofsA[2][2];
    #pragma unroll
    for (int h = 0; h < 2; ++h)
        #pragma unroll
        for (int j = 0; j < 2; ++j) {
            const int rowOff = h * 128 + j * 64 + w * 8 + r8;
            gA[h][j] = Ap + (rowBase + rowOff) * (long)K + cg * 8;
            lofsA[h][j] = (h * 128 + j * 64 + w * 8) * 64;       // shorts
        }
    const unsigned short* gB[LB];
    int lofsB[LB];
    #pragma unroll
    for (int j = 0; j < LB; ++j) {
        const int rowOff = j * 64 + w * 8 + r8;
        gB[j] = Bp + (colBase + rowOff) * (long)K + cg * 8;
        lofsB[j] = (j * 64 + w * 8) * 64;
    }

    const int nT = K >> 6;
    f32x4 acc[8][FC] = {};

    // prologue: stage t0.A, t0.B, t1.B; A ptrs -> t1, B ptrs -> t2
    #pragma unroll
    for (int h = 0; h < 2; ++h)
        #pragma unroll
        for (int j = 0; j < 2; ++j) { load_lds16(gA[h][j], &As[0][lofsA[h][j]]); gA[h][j] += 64; }
    #pragma unroll
    for (int j = 0; j < LB; ++j) { load_lds16(gB[j], &Bs[0][lofsB[j]]); gB[j] += 64; }
    if (nT > 1) {
        #pragma unroll
        for (int j = 0; j < LB; ++j) { load_lds16(gB[j], &Bs[1][lofsB[j]]); gB[j] += 64; }
        __builtin_amdgcn_s_waitcnt(0x0F70 | LB);  // t0 landed; t1.B may fly
    } else {
        __builtin_amdgcn_s_waitcnt(0x0F70);
    }
    raw_barrier();

    for (int t = 0; t < nT; ++t) {
        const int cb = t & 1;
        const unsigned short* Ac = As[cb];
        const unsigned short* Bc = Bs[cb];
        unsigned short* Anx = As[cb ^ 1];    // tile t+1
        unsigned short* Bnx = Bs[cb];        // tile t+2 (same parity)
        const bool stA = (t + 1 < nT);
        const bool stB = (t + 2 < nT);
        bf16x8 bfr[FC][2];
        bf16x8 af[2][2];

        // phase 0: all B frags + A rows 0/1; stage A-half0 of t+1
        #pragma unroll
        for (int fc = 0; fc < FC; ++fc)
            #pragma unroll
            for (int ks = 0; ks < 2; ++ks)
                bfr[fc][ks] = *(const bf16x8*)&Bc[(wc + fc * 16 + l16) * 64
                                                 + ((ks * 4 + quad) ^ (l16 & 7)) * 8];
        P8_RD_A(0)
        if (stA) P8_STG_A(0);
        raw_barrier();
        P8_MFMA(0)
        raw_barrier();

        // phase 1: A rows 2/3; stage A-half1 of t+1
        P8_RD_A(1)
        if (stA) P8_STG_A(1);
        raw_barrier();
        P8_MFMA(1)
        raw_barrier();

        // phase 2: A rows 4/5; stage first half of B(t+2)
        P8_RD_A(2)
        if (stB) {
            #pragma unroll
            for (int j = 0; j < (LB + 1) / 2; ++j) P8_STG_B(j);
        }
        raw_barrier();
        P8_MFMA(2)
        raw_barrier();

        // phase 3: A rows 6/7; stage rest of B(t+2); counted vmcnt
        P8_RD_A(3)
        if (stB) {
            #pragma unroll
            for (int j = (LB + 1) / 2; j < LB; ++j) P8_STG_B(j);
            __builtin_amdgcn_s_waitcnt(0x0F70 | LB);  // t+1 landed; t+2.B may fly
        } else {
            __builtin_amdgcn_s_waitcnt(0x0F70);       // tail: drain
        }
        raw_barrier();
        P8_MFMA(3)
        raw_barrier();
    }

    char* Cb = (char*)Cv + (long)bz * sCb;
    float* Cf = (float*)Cb;
    unsigned short* Ch = (unsigned short*)Cb;
    #pragma unroll
    for (int i = 0; i < 8; ++i)
        #pragma unroll
        for (int r = 0; r < 4; ++r) {
            long gr = rowBase + wr + i * 16 + quad * 4 + r;
            #pragma unroll
            for (int j = 0; j < FC; ++j) {
                long gc = colBase + wc + j * 16 + l16;
                long off = gr * (long)Mc + gc;
                float v = acc[i][j][r];
                if (epi == 0)      Cf[off] = v;
                else if (epi == 2) Ch[off] = f2bf(v);
                else if (epi == 3) Ch[off] = f2bf(silu(v));
                else               Ch[off] = f2bf(bf2f(rh[off]) - v);   // epi 7: err
            }
        }
}

// ---------------- tiled transpose (+convert) to bf16, batched via z
template <typename TS>
__global__ void k_transpose(const TS* __restrict__ src, unsigned short* __restrict__ dst,
                            int R, int C, int dstLd, int dstOff, long sSrc, long sDst)
{
    __shared__ float tile[32][33];
    const TS* sp = src + (long)blockIdx.z * sSrc;
    unsigned short* dp = dst + (long)blockIdx.z * sDst;
    int c0 = blockIdx.x * 32, r0 = blockIdx.y * 32;
    int tx = threadIdx.x, ty = threadIdx.y;     // 32 x 8
    #pragma unroll
    for (int i = 0; i < 4; ++i)
        tile[ty + i * 8][tx] = ldf(&sp[(long)(r0 + ty + i * 8) * C + c0 + tx]);
    __syncthreads();
    #pragma unroll
    for (int i = 0; i < 4; ++i)
        dp[(long)(c0 + ty + i * 8) * dstLd + dstOff + r0 + tx] = f2bf(tile[tx][ty + i * 8]);
}

// z0: eT[m][n] = errN[n][m]; z1: kT[m][n] = k_bf[n][m]  (both bf16)
__global__ void k_errT_kT(const unsigned short* __restrict__ errN,
                          const unsigned short* __restrict__ k_bf, unsigned short* __restrict__ eT)
{
    __shared__ float tile[32][33];
    int z = blockIdx.z;
    const unsigned short* src = (z == 0) ? errN : k_bf;
    int c0 = blockIdx.x * 32, r0 = blockIdx.y * 32;
    int tx = threadIdx.x, ty = threadIdx.y;
    #pragma unroll
    for (int i = 0; i < 4; ++i) {
        long idx = (long)(r0 + ty + i * 8) * MD + c0 + tx;
        tile[ty + i * 8][tx] = bf2f(src[idx]);
    }
    __syncthreads();
    unsigned short* dst = eT + (long)z * NM;
    #pragma unroll
    for (int i = 0; i < 4; ++i)
        dst[(long)(c0 + ty + i * 8) * MD + r0 + tx] = f2bf(tile[tx][ty + i * 8]);
}

// snapT[h][d] = bf16((1-a)*mem[d][h] + eta*sur[d][h] + (theta/2048)*momT[h][d])
__global__ void k_snapT(const float* __restrict__ mem, const float* __restrict__ sur,
                        const float* __restrict__ momT, const float* __restrict__ scal,
                        unsigned short* __restrict__ dst)
{
    __shared__ float tile[32][33];
    float eta = scal[0], theta = scal[1], alpha = scal[2];
    int h0 = blockIdx.y * 32, d0 = blockIdx.x * 32;
    int tx = threadIdx.x, ty = threadIdx.y;
    #pragma unroll
    for (int i = 0; i < 4; ++i) {
        long idx = (long)(d0 + ty + i * 8) * MD + h0 + tx;
        tile[ty + i * 8][tx] = (1.f - alpha) * mem[idx] + eta * sur[idx];
    }
    __syncthreads();
    #pragma unroll
    for (int i = 0; i < 4; ++i) {
        long oidx = (long)(h0 + ty + i * 8) * MD + d0 + tx;
        dst[oidx] = f2bf(tile[tx][ty + i * 8] + theta * (1.f / 2048.f) * momT[oidx]);
    }
}

// ---------------- fused / vectorized elementwise ----------------
__global__ void k_cvt_multi(const float* s0, const float* s1, const float* s2, const float* s3,
                            const float* s4, const float* s5, const float* s6, const float* s7,
                            unsigned short* d0, unsigned short* d1, unsigned short* d2, unsigned short* d3,
                            unsigned short* d4, unsigned short* d5, unsigned short* d6, unsigned short* d7)
{
    int seg = blockIdx.x >> 11;
    const float* s; unsigned short* d;
    switch (seg) {
        case 0: s = s0; d = d0; break;  case 1: s = s1; d = d1; break;
        case 2: s = s2; d = d2; break;  case 3: s = s3; d = d3; break;
        case 4: s = s4; d = d4; break;  case 5: s = s5; d = d5; break;
        case 6: s = s6; d = d6; break;  default: s = s7; d = d7; break;
    }
    long idx = ((long)(blockIdx.x & 2047) * 256 + threadIdx.x) * 8;
    float4 a = *(const float4*)(s + idx);
    float4 b = *(const float4*)(s + idx + 4);
    u16x8 o;
    o[0] = f2bf(a.x); o[1] = f2bf(a.y); o[2] = f2bf(a.z); o[3] = f2bf(a.w);
    o[4] = f2bf(b.x); o[5] = f2bf(b.y); o[6] = f2bf(b.z); o[7] = f2bf(b.w);
    *(u16x8*)(d + idx) = o;
}

// depthwise causal conv z3, vec8. tproj: [2048][6144] bf16; conv: [3][2048][2048]
__global__ void k_dwconv(const unsigned short* __restrict__ tproj,
                         const float* __restrict__ qdw, const float* __restrict__ kdw,
                         const float* __restrict__ vdw, unsigned short* __restrict__ conv)
{
    long u = (long)blockIdx.x * 256 + threadIdx.x;
    long flat = u * 8;
    int z = (int)(flat >> 22);
    int rem = (int)(flat & (NM - 1));
    int n = rem >> 11, m = rem & 2047;
    int l = n & 1023;
    const float* dw = (z == 0) ? qdw : (z == 1) ? kdw : vdw;
    const unsigned short* src = tproj + (long)n * 6144 + z * 2048 + m;
    float4 dwv[8];
    #pragma unroll
    for (int e = 0; e < 8; ++e) dwv[e] = *(const float4*)(dw + (m + e) * 4);
    float acc[8] = {};
    #pragma unroll
    for (int j = 0; j < 4; ++j) {
        int dl = j - 3;
        if (l + dl >= 0) {
            u16x8 r = *(const u16x8*)(src + (long)dl * 6144);
            #pragma unroll
            for (int e = 0; e < 8; ++e)
                acc[e] += ((const float*)&dwv[e])[j] * bf2f(r[e]);
        }
    }
    u16x8 o;
    #pragma unroll
    for (int e = 0; e < 8; ++e) o[e] = f2bf(acc[e]);
    *(u16x8*)(conv + (long)z * NM + (long)n * 2048 + m) = o;
}

// post-pointwise on silu'd bf16 rows: z0: l2n -> q_bf ; z1: l2n -> k_bf + kwp
__global__ void k_post_qkv(const unsigned short* __restrict__ tbf, unsigned short* __restrict__ q_bf,
                           unsigned short* __restrict__ k_bf, unsigned short* __restrict__ kwp)
{
    int bid = blockIdx.x, z = bid >> 11, n = bid & 2047;
    const unsigned short* row = tbf + (long)z * NM + (long)n * 2048;
    int t = threadIdx.x;
    u16x8 iv = *(const u16x8*)(row + t * 8);
    float v[8];
    #pragma unroll
    for (int e = 0; e < 8; ++e) v[e] = bf2f(iv[e]);
    float ss = 0.f;
    #pragma unroll
    for (int e = 0; e < 8; ++e) ss += v[e] * v[e];
    ss = block_reduce_sum(ss);
    float inv = 1.f / (sqrtf(ss) + 1e-6f);
    u16x8 o;
    #pragma unroll
    for (int e = 0; e < 8; ++e) o[e] = f2bf(v[e] * inv);
    if (z == 0) {
        *(u16x8*)(q_bf + (long)n * 2048 + t * 8) = o;
    } else {
        *(u16x8*)(k_bf + (long)n * 2048 + t * 8) = o;
        int bb = n >> 10, l = n & 1023;
        *(u16x8*)(kwp + ((long)bb * PLP + 8 + l) * MD + t * 8) = o;
    }
}

// misc: pkn rows (8) | pv->vwpT (64) | kwp tail zero (240) | vwpT tail zero (240)
__global__ void k_misc(const float* __restrict__ pk, const float* __restrict__ pv,
                       unsigned short* __restrict__ kwp, unsigned short* __restrict__ vwpT)
{
    int bid = blockIdx.x, t = threadIdx.x;
    if (bid < 8) {
        const float* row = pk + bid * MD;
        float4 a = *(const float4*)(row + t * 8);
        float4 b = *(const float4*)(row + t * 8 + 4);
        float v[8] = {a.x, a.y, a.z, a.w, b.x, b.y, b.z, b.w};
        float ss = 0.f;
        #pragma unroll
        for (int e = 0; e < 8; ++e) ss += v[e] * v[e];
        ss = block_reduce_sum(ss);
        float inv = 1.f / (sqrtf(ss) + 1e-6f);
        u16x8 o;
        #pragma unroll
        for (int e = 0; e < 8; ++e) o[e] = f2bf(v[e] * inv);
        *(u16x8*)(kwp + (long)bid * MD + t * 8) = o;
        *(u16x8*)(kwp + (long)PLP * MD + (long)bid * MD + t * 8) = o;
    } else if (bid < 72) {
        int i = (bid - 8) * 256 + t;         // 16384 = 2048*8
        int m = i >> 3, pp = i & 7;
        unsigned short h = f2bf(pv[pp * MD + m]);
        vwpT[(long)m * PLP + pp] = h;
        vwpT[(long)MD * PLP + (long)m * PLP + pp] = h;
    } else if (bid < 312) {
        long flat = ((long)(bid - 72) * 256 + t) * 8;    // 2*120*2048
        int b = (int)(flat / 245760);
        int r = (int)(flat % 245760);
        int j = 1032 + (r >> 11), m = r & 2047;
        u16x8 zz = {};
        *(u16x8*)(kwp + ((long)b * PLP + j) * MD + m) = zz;
    } else {
        long flat = ((long)(bid - 312) * 256 + t) * 8;   // 2*2048*120
        int bm = (int)(flat / 120);
        int o = (int)(flat % 120);
        u16x8 zz = {};
        *(u16x8*)(vwpT + (long)bm * PLP + 1032 + o) = zz;
    }
}

// pooled dots (eta/theta/alpha) + x -> bf16 convert, fused; NO atomics:
// per-block partials -> part[3][2][128], reduced in k_scal_fin.
__global__ void k_pooled(const float* __restrict__ x, const float* __restrict__ ew,
                         const float* __restrict__ tw, const float* __restrict__ aw,
                         float* __restrict__ part, unsigned short* __restrict__ xbf) {
    int b = blockIdx.y;
    long base = (long)b * 1024 * MD;
    long start = (long)blockIdx.x * 16384;
    float s0 = 0.f, s1 = 0.f, s2 = 0.f;
    #pragma unroll
    for (int s = 0; s < 8; ++s) {
        long flat = start + ((long)s * 256 + threadIdx.x) * 8;
        long gi = base + flat;
        int d = (int)(flat & (MD - 1));
        float4 a = *(const float4*)(x + gi);
        float4 b4 = *(const float4*)(x + gi + 4);
        float xv[8] = {a.x, a.y, a.z, a.w, b4.x, b4.y, b4.z, b4.w};
        u16x8 o;
        #pragma unroll
        for (int e = 0; e < 8; ++e) o[e] = f2bf(xv[e]);
        *(u16x8*)(xbf + gi) = o;
        float4 e0 = *(const float4*)(ew + d), e1 = *(const float4*)(ew + d + 4);
        float4 t0 = *(const float4*)(tw + d), t1 = *(const float4*)(tw + d + 4);
        float4 w0 = *(const float4*)(aw + d), w1 = *(const float4*)(aw + d + 4);
        s0 += xv[0]*e0.x + xv[1]*e0.y + xv[2]*e0.z + xv[3]*e0.w
            + xv[4]*e1.x + xv[5]*e1.y + xv[6]*e1.z + xv[7]*e1.w;
        s1 += xv[0]*t0.x + xv[1]*t0.y + xv[2]*t0.z + xv[3]*t0.w
            + xv[4]*t1.x + xv[5]*t1.y + xv[6]*t1.z + xv[7]*t1.w;
        s2 += xv[0]*w0.x + xv[1]*w0.y + xv[2]*w0.z + xv[3]*w0.w
            + xv[4]*w1.x + xv[5]*w1.y + xv[6]*w1.z + xv[7]*w1.w;
    }
    s0 = block_reduce_sum(s0);
    if (threadIdx.x == 0) part[0 * 256 + b * 128 + blockIdx.x] = s0;
    s1 = block_reduce_sum(s1);
    if (threadIdx.x == 0) part[1 * 256 + b * 128 + blockIdx.x] = s1;
    s2 = block_reduce_sum(s2);
    if (threadIdx.x == 0) part[2 * 256 + b * 128 + blockIdx.x] = s2;
}
__global__ void k_scal_fin(const float* __restrict__ part, const float* __restrict__ eb,
                           const float* __restrict__ tb, const float* __restrict__ ab,
                           float* __restrict__ scal) {
    int t = threadIdx.x;   // 256 threads
    float v[6];
    #pragma unroll
    for (int c = 0; c < 3; ++c)
        #pragma unroll
        for (int b = 0; b < 2; ++b)
            v[c * 2 + b] = (t < 128) ? part[c * 256 + b * 128 + t] : 0.f;
    float d00 = block_reduce_sum(v[0]);
    float d01 = block_reduce_sum(v[1]);
    float d10 = block_reduce_sum(v[2]);
    float d11 = block_reduce_sum(v[3]);
    float d20 = block_reduce_sum(v[4]);
    float d21 = block_reduce_sum(v[5]);
    if (t == 0) {
        const float invL = 1.f / 1024.f;
        scal[0] = 0.5f * (sigm(d00 * invL + eb[0]) + sigm(d01 * invL + eb[0]));
        scal[1] = 0.5f * (sigm(d10 * invL + tb[0]) + sigm(d11 * invL + tb[0]));
        scal[2] = 0.5f * (sigm(d20 * invL + ab[0]) + sigm(d21 * invL + ab[0]));
    }
}

__global__ void k_softmax(const float* __restrict__ S, unsigned short* __restrict__ attn) {
    int l = blockIdx.x, b = blockIdx.y;
    long base = ((long)b * 1024 + l) * PLP;
    int nvis = 8 + l + 1;
    const float scale = 0.022097086912079608f;  // 1/sqrt(2048)
    int t = threadIdx.x;
    float vals[5];
    float mx = -1e30f;
    #pragma unroll
    for (int s = 0; s < 5; ++s) {
        int j = t + s * 256;
        float v = -1e30f;
        if (j < nvis) v = S[base + j] * scale;
        vals[s] = v;
        mx = fmaxf(mx, v);
    }
    mx = block_reduce_max(mx);
    float sum = 0.f;
    #pragma unroll
    for (int s = 0; s < 5; ++s) {
        int j = t + s * 256;
        float e = 0.f;
        if (j < nvis) e = __expf(vals[s] - mx);
        vals[s] = e; sum += e;
    }
    sum = block_reduce_sum(sum);
    float inv = 1.f / sum;
    #pragma unroll
    for (int s = 0; s < 5; ++s) {
        int j = t + s * 256;
        if (j < PLP) attn[base + j] = f2bf(vals[s] * inv);
    }
}

__global__ void k_final(const float* __restrict__ x, const float* __restrict__ y,
                        const float* __restrict__ lnw, float* __restrict__ out) {
    int n = blockIdx.x;
    long base = (long)n * MD;
    int t = threadIdx.x;
    float4 a0 = *(const float4*)(x + base + t * 8), a1 = *(const float4*)(x + base + t * 8 + 4);
    float4 b0 = *(const float4*)(y + base + t * 8), b1 = *(const float4*)(y + base + t * 8 + 4);
    float v[8] = {a0.x + b0.x, a0.y + b0.y, a0.z + b0.z, a0.w + b0.w,
                  a1.x + b1.x, a1.y + b1.y, a1.z + b1.z, a1.w + b1.w};
    float ss = 0.f;
    #pragma unroll
    for (int e = 0; e < 8; ++e) ss += v[e] * v[e];
    ss = block_reduce_sum(ss);
    float inv = rsqrtf(ss * (1.f / 2048.f) + 1e-6f);
    float4 w0 = *(const float4*)(lnw + t * 8), w1 = *(const float4*)(lnw + t * 8 + 4);
    float4 o0 = {v[0] * inv * w0.x, v[1] * inv * w0.y, v[2] * inv * w0.z, v[3] * inv * w0.w};
    float4 o1 = {v[4] * inv * w1.x, v[5] * inv * w1.y, v[6] * inv * w1.z, v[7] * inv * w1.w};
    *(float4*)(out + base + t * 8) = o0;
    *(float4*)(out + base + t * 8 + 4) = o1;
}

// ---------------- host-side ----------------
static inline void gemm64(hipStream_t st, const void* A, const void* B, void* C,
                          int Mc, int K, long sA, long sB, long sCb,
                          int gx, int gy, int gz, int epiPack,
                          const float* gbp = nullptr, const float* r1 = nullptr,
                          const float* r2 = nullptr, unsigned short* qh = nullptr) {
    hipLaunchKernelGGL(gemm_nt, dim3(gx, gy, gz), dim3(256), 0, st,
                       (const unsigned short*)A, (const unsigned short*)B, C,
                       Mc, K, sA, sB, sCb, epiPack, gbp, r1, r2, qh);
}
static inline void gemm128(hipStream_t st, const void* A, const void* B, void* C,
                           int Mc, int K, long sA, long sB, long sCb,
                           int gx, int gy, int gz, int epiPack,
                           const unsigned short* rh = nullptr) {
    hipLaunchKernelGGL(gemm_nt_big, dim3(gx, gy, gz), dim3(256), 0, st,
                       (const unsigned short*)A, (const unsigned short*)B, C,
                       Mc, K, sA, sB, sCb, epiPack, rh);
}
template <int BN>
static inline void gemm8p(hipStream_t st, const void* A, const void* B, void* C,
                          int Mc, int K, long sA, long sB, long sCb,
                          int gx, int gy, int gz, int epiPack,
                          const unsigned short* rh = nullptr) {
    hipLaunchKernelGGL(gemm_nt_8p<BN>, dim3(gx, gy, gz), dim3(512), 0, st,
                       (const unsigned short*)A, (const unsigned short*)B, C,
                       Mc, K, sA, sB, sCb, epiPack, rh);
}

extern "C" void kernel_launch(void* const* d_in, const int* in_sizes, int n_in,
                              void* d_out, int out_size, void* d_ws, size_t ws_size,
                              hipStream_t stream) {
    const float* x    = (const float*)d_in[0];
    const float* Wq   = (const float*)d_in[1];
    const float* Wk   = (const float*)d_in[2];
    const float* Wv   = (const float*)d_in[3];
    const float* qdw  = (const float*)d_in[4];
    const float* kdw  = (const float*)d_in[5];
    const float* vdw  = (const float*)d_in[6];
    const float* qpw  = (const float*)d_in[7];
    const float* kpw  = (const float*)d_in[8];
    const float* vpw  = (const float*)d_in[9];
    const float* pk   = (const float*)d_in[10];
    const float* pv   = (const float*)d_in[11];
    const float* mw1  = (const float*)d_in[12];
    const float* mw2  = (const float*)d_in[13];
    const float* etaw = (const float*)d_in[14];
    const float* etab = (const float*)d_in[15];
    const float* thw  = (const float*)d_in[16];
    const float* thb  = (const float*)d_in[17];
    const float* alw  = (const float*)d_in[18];
    const float* alb  = (const float*)d_in[19];
    const float* gw   = (const float*)d_in[20];
    const float* gb   = (const float*)d_in[21];
    const float* ow   = (const float*)d_in[22];
    const float* lnw  = (const float*)d_in[23];
    const float* mem  = (const float*)d_in[24];
    const float* sur  = (const float*)d_in[25];
    float* out = (float*)d_out;

    char* ws = (char*)d_ws;
    const size_t MB = 1024 * 1024;
    float* part = (float*)ws;                    // 3*2*128 floats = 3 KB
    float* scal = (float*)(ws + 3584);
    // memory map (160 MB + 4 KB):
    float*          t0f  = (float*)(ws + 4096);                 // 48MB region A
    float*          t1f  = t0f + NM;
    float*          t2f  = t0f + 2 * NM;
    unsigned short* tproj = (unsigned short*)t0f;               // overlays (24MB)
    unsigned short* t_bf  = (unsigned short*)t0f;               // G2 silu'd bf16 [3][NM]
    unsigned short* vf    = t_bf + 2 * (long)NM;                // z2 slice == vf
    float*          retf = (float*)(ws + 4096 + 48 * MB);       // 16MB
    unsigned short* k_bf = (unsigned short*)(ws + 4096 + 64 * MB);  // 8MB
    unsigned short* q_bf = k_bf + NM;                               // 8MB
    unsigned short* qc   = k_bf + 2 * NM;                           // 8MB (silu(mlp1), later rg)
    unsigned short* g_bf = k_bf;                                    // reuse after errT/kT
    unsigned short* x_bf = (unsigned short*)(ws + 4096 + 88 * MB);  // 8MB (later errN, attn)
    unsigned short* errN = x_bf;
    unsigned short* attn = x_bf;
    unsigned short* wQKV = (unsigned short*)(ws + 4096 + 96 * MB);  // 24MB region E
    unsigned short* conv = wQKV;
    unsigned short* kwp  = wQKV;
    unsigned short* vwpT = kwp + (long)2 * PLP * MD;
    unsigned short* wPW  = (unsigned short*)(ws + 4096 + 120 * MB); // 24MB region F
    unsigned short* eT   = wPW;
    unsigned short* kT   = eT + NM;
    unsigned short* gw_bf = wPW;
    unsigned short* ow_bf = wPW + NM;
    unsigned short* wMem  = (unsigned short*)(ws + 4096 + 144 * MB); // 16MB region G
    unsigned short* wMlp1 = wMem + NM;
    unsigned short* wSnap = wMem;
    unsigned short* wMlp2 = wMem + NM;

    const dim3 b256(256);
    const dim3 bT(32, 8);

    // 1. scalars + x -> bf16 (fused, atomic-free)
    hipLaunchKernelGGL(k_pooled, dim3(128, 2), b256, 0, stream, x, etaw, thw, alw, part, x_bf);
    hipLaunchKernelGGL(k_scal_fin, dim3(1), b256, 0, stream, part, etab, thb, alb, scal);
    // 2. converts: Wq, Wk, Wv, qpw, kpw, vpw, mw1 (7 segs)
    hipLaunchKernelGGL(k_cvt_multi, dim3(14336), b256, 0, stream,
                       Wq, Wk, Wv, qpw, kpw, vpw, mw1, mw1,
                       wQKV, wQKV + NM, wQKV + 2 * (long)NM,
                       wPW, wPW + NM, wPW + 2 * (long)NM, wMlp1, wMlp1);
    // 3. mem -> wMem (transposed bf16)
    hipLaunchKernelGGL(k_transpose<float>, dim3(64, 64, 1), bT, 0, stream,
                       mem, wMem, MD, MD, MD, 0, 0L, 0L);
    // 4. G1 (256x256, grid 192): wide qkv projection -> tproj bf16 [2048][6144]
    gemm8p<256>(stream, x_bf, wQKV, tproj, 6144, MD, 0, 0, 0, 24, 8, 1, 0x2);
    // 5. depthwise conv z3 -> conv
    hipLaunchKernelGGL(k_dwconv, dim3(6144), b256, 0, stream, tproj, qdw, kdw, vdw, conv);
    // 6. G2 (256x256): pointwise z3 -> silu'd bf16 t_bf (z2 == vf, no copy)
    gemm8p<256>(stream, conv, wPW, t_bf, MD, MD, NM, NM, (long)NM * 2, 8, 8, 3, 0x333);
    // 7. misc (kwp p-rows, vwpT p-cols, zero tails)
    hipLaunchKernelGGL(k_misc, dim3(552), b256, 0, stream, pk, pv, kwp, vwpT);
    // 8. post qkv (z0/z1): l2n -> q_bf, k_bf(+kwp)
    hipLaunchKernelGGL(k_post_qkv, dim3(4096), b256, 0, stream, t_bf, q_bf, k_bf, kwp);
    // 9. vf -> vwpT (transposed, offset 8)
    hipLaunchKernelGGL(k_transpose<unsigned short>, dim3(64, 32, 2), bT, 0, stream,
                       vf, vwpT, 1024, MD, PLP, 8, (long)1024 * MD, (long)MD * PLP);
    // 10. G3 (128x128, grid 512) z2: errN = bf16(vf - k.memT) ; mlp1 -> silu bf16 -> qc
    gemm128(stream, k_bf, wMem, errN, MD, MD, NM, NM,
            (long)((char*)qc - (char*)errN), 16, 16, 2, 0x37, vf);
    // 11. errT / kT (bf16 transposes)
    hipLaunchKernelGGL(k_errT_kT, dim3(64, 64, 2), bT, 0, stream, errN, k_bf, eT);
    // 12. G4: momT = eT.kT -> t2f
    gemm64(stream, eT, kT, t2f, MD, MD, 0, 0, 0, 32, 16, 1, 0);
    // 13. snapT -> wSnap
    hipLaunchKernelGGL(k_snapT, dim3(64, 64), bT, 0, stream, mem, sur, t2f, scal, wSnap);
    // 14. converts: mw2, gw, ow
    hipLaunchKernelGGL(k_cvt_multi, dim3(6144), b256, 0, stream,
                       mw2, gw, ow, mw2, mw2, mw2, mw2, mw2,
                       wMlp2, gw_bf, ow_bf, wMlp2, wMlp2, wMlp2, wMlp2, wMlp2);
    // 15. G5 (128x128, grid 512) z2: linret = q.snapT -> retf ; mlp2 = qc.wMlp2 -> t1f
    gemm128(stream, q_bf, wSnap, retf, MD, MD, NM, NM,
            (long)((char*)t1f - (char*)retf), 16, 16, 2, 0x00);
    // 16. G6: scores z2 -> t2f
    gemm64(stream, q_bf, kwp, t2f, PLP, MD,
           (long)1024 * MD, (long)PLP * MD, (long)1024 * PLP * 4, 18, 8, 2, 0);
    // 17. softmax -> attn bf16
    hipLaunchKernelGGL(k_softmax, dim3(1024, 2), b256, 0, stream, t2f, attn);
    // 18. G7: context z2, epi5: retf += ctx AND qc = bf16(retf + mlp2)
    gemm64(stream, attn, vwpT, retf, MD, PLP,
           (long)1024 * PLP, (long)MD * PLP, (long)1024 * MD * 4, 32, 8, 2, 0x55,
           nullptr, retf, t1f, qc);
    // 19. G8 epi4: g_bf = bf16(sigm(rg.gwT + gb) * (retf + mlp2))
    gemm64(stream, qc, gw_bf, g_bf, MD, MD, 0, 0, 0, 32, 16, 1, 4,
           gb, retf, t1f, nullptr);
    // 20. G9: outproj = g.owT -> t0f
    gemm64(stream, g_bf, ow_bf, t0f, MD, MD, 0, 0, 0, 32, 16, 1, 0);
    // 21. final RMSNorm
    hipLaunchKernelGGL(k_final, dim3(2048), b256, 0, stream, x, t0f, lnw, out);
}